// Round 1
// baseline (644.258 us; speedup 1.0000x reference)
//
#include <hip/hip_runtime.h>
#include <math.h>

// PrototypicalLoss: B=8192, N=64, D=256 fp32.
// One wave (64 lanes) per batch element. Lane l owns floats [4l, 4l+4) of D.
// Key bandwidth trick: only support rows with label==1 are ever read
// (~50% of the 512 MiB input), each read is a full contiguous 1 KiB row.

__global__ __launch_bounds__(256) void proto_dist_kernel(
    const float* __restrict__ query,    // (B, 256)
    const float* __restrict__ support,  // (B, 64, 256)
    const int*   __restrict__ labels,   // (B, 64)
    float* __restrict__ dists,          // (B,)
    int B)
{
    const int lane = threadIdx.x & 63;
    const int wv   = threadIdx.x >> 6;
    const int b    = blockIdx.x * 4 + wv;
    if (b >= B) return;

    // one label per lane -> wave-uniform 64-bit mask
    const int lab = labels[(size_t)b * 64 + lane];
    const unsigned long long m = __ballot(lab == 1);
    const int count = __popcll(m);

    // support rows for this b, viewed as 64 float4 per row
    const float4* srow = (const float4*)(support + (size_t)b * 64 * 256);

    float4 acc = make_float4(0.f, 0.f, 0.f, 0.f);
    unsigned long long mm = m;
    while (mm) {                       // wave-uniform loop, no divergence
        const int n = __builtin_ctzll(mm);
        mm &= (mm - 1);
        const float4 v = srow[(size_t)n * 64 + lane];
        acc.x += v.x; acc.y += v.y; acc.z += v.z; acc.w += v.w;
    }

    float4 proto;
    if (count > 0) {                   // wave-uniform branch
        const float inv = 1.0f / (float)count;
        proto = make_float4(acc.x * inv, acc.y * inv, acc.z * inv, acc.w * inv);
    } else {
        proto = srow[lane];            // fallback: support[b, 0, :]
    }

    const float4 q = ((const float4*)(query + (size_t)b * 256))[lane];
    const float dx = q.x - proto.x;
    const float dy = q.y - proto.y;
    const float dz = q.z - proto.z;
    const float dw = q.w - proto.w;
    float ss = dx * dx + dy * dy + dz * dz + dw * dw;

    // reduce across the 64-lane wave
    #pragma unroll
    for (int off = 32; off > 0; off >>= 1)
        ss += __shfl_down(ss, off, 64);

    if (lane == 0)
        dists[b] = sqrtf(ss + 1e-8f);
}

__global__ __launch_bounds__(256) void reduce_mean_kernel(
    const float* __restrict__ dists, float* __restrict__ out, int B)
{
    __shared__ float sm[4];
    float s = 0.f;
    for (int i = threadIdx.x; i < B; i += 256)
        s += dists[i];
    #pragma unroll
    for (int off = 32; off > 0; off >>= 1)
        s += __shfl_down(s, off, 64);
    const int lane = threadIdx.x & 63;
    const int wv   = threadIdx.x >> 6;
    if (lane == 0) sm[wv] = s;
    __syncthreads();
    if (threadIdx.x == 0)
        out[0] = (sm[0] + sm[1] + sm[2] + sm[3]) / (float)B;
}

extern "C" void kernel_launch(void* const* d_in, const int* in_sizes, int n_in,
                              void* d_out, int out_size, void* d_ws, size_t ws_size,
                              hipStream_t stream) {
    const float* query   = (const float*)d_in[0];   // (B, D) fp32
    const float* support = (const float*)d_in[1];   // (B, N, D) fp32
    const int*   labels  = (const int*)d_in[2];     // (B, N) int32
    float* out = (float*)d_out;

    const int n_q = in_sizes[0];
    const int n_s = in_sizes[1];
    const int n_l = in_sizes[2];
    const int D = n_s / n_l;        // 256
    const int B = n_q / D;          // 8192
    // N = n_l / B = 64 (kernel hard-assumes N=64, D=256 per the reference)
    (void)n_in; (void)out_size; (void)ws_size;

    float* dists = (float*)d_ws;    // B floats of scratch

    const int blocks = (B + 3) / 4; // 4 waves (batch elems) per 256-thread block
    proto_dist_kernel<<<blocks, 256, 0, stream>>>(query, support, labels, dists, B);
    reduce_mean_kernel<<<1, 256, 0, stream>>>(dists, out, B);
}